// Round 1
// baseline (127.101 us; speedup 1.0000x reference)
//
#include <hip/hip_runtime.h>
#include <math.h>

#define NB 8
#define NHEADS 8
#define NDK 32
#define NDV 64
#define NSEQ 1024
#define NCIN 256

typedef __attribute__((ext_vector_type(8))) short bf16x8;
typedef __attribute__((ext_vector_type(4))) float f32x4;

// guide §3: short8 frag type, compile-verified on gfx950 (learn_hip examples)
#define MFMA16(A, B, C) __builtin_amdgcn_mfma_f32_16x16x32_bf16(A, B, C, 0, 0, 0)

__device__ __forceinline__ short f2bf(float f) {
    union { float f; unsigned u; } v; v.f = f;
    unsigned r = v.u + 0x7FFFu + ((v.u >> 16) & 1u);
    return (short)(r >> 16);
}

// ---------------- K0: fold BN into weights, convert to bf16 ----------------
__global__ __launch_bounds__(256) void prep_kernel(
    const float* __restrict__ wq, const float* __restrict__ qg, const float* __restrict__ qb,
    const float* __restrict__ qm, const float* __restrict__ qv,
    const float* __restrict__ wk, const float* __restrict__ kg, const float* __restrict__ kb,
    const float* __restrict__ km, const float* __restrict__ kv,
    const float* __restrict__ wv, const float* __restrict__ vg, const float* __restrict__ vb,
    const float* __restrict__ vm, const float* __restrict__ vv,
    const float* __restrict__ wo,
    short* __restrict__ Wqkv, float* __restrict__ Bqkv, short* __restrict__ Wo)
{
    int row = blockIdx.x, t = threadIdx.x;
    if (row < 1024) {
        const float *w, *g, *be, *mu, *va; int o;
        if (row < 256)      { w = wq; o = row;       g = qg; be = qb; mu = qm; va = qv; }
        else if (row < 512) { w = wk; o = row - 256; g = kg; be = kb; mu = km; va = kv; }
        else                { w = wv; o = row - 512; g = vg; be = vb; mu = vm; va = vv; }
        float inv = g[o] * rsqrtf(va[o] + 1e-5f);
        Wqkv[row * NCIN + t] = f2bf(w[o * NCIN + t] * inv);
        if (t == 0) Bqkv[row] = be[o] - mu[o] * inv;
    } else {
        int o = row - 1024;
        Wo[o * 512 + t]       = f2bf(wo[o * 512 + t]);
        Wo[o * 512 + 256 + t] = f2bf(wo[o * 512 + 256 + t]);
    }
}

// ---------------- K1: x (b,c,p) f32 -> Xt (b,p,c) bf16 ----------------
__global__ __launch_bounds__(256) void transpose_kernel(const float* __restrict__ x, short* __restrict__ Xt)
{
    __shared__ float tile[64][65];
    int b = blockIdx.z, p0 = blockIdx.x * 64, c0 = blockIdx.y * 64;
    int t = threadIdx.x, tp = t & 63, tr = t >> 6;
    const float* xb = x + ((size_t)b * NCIN + c0) * NSEQ + p0;
#pragma unroll
    for (int i = 0; i < 16; ++i) {
        int cl = tr * 16 + i;
        tile[cl][tp] = xb[(size_t)cl * NSEQ + tp];
    }
    __syncthreads();
    short* xt = Xt + ((size_t)b * NSEQ + p0) * NCIN + c0;
#pragma unroll
    for (int i = 0; i < 16; ++i) {
        int pl = tr * 16 + i;
        xt[(size_t)pl * NCIN + tp] = f2bf(tile[tp][pl]);
    }
}

// ---------------- K2: QKV projection GEMM ----------------
// Y[b][p][o] = sum_c Xt[b][p][c] * Wqkv[o][c] + Bqkv[o]; scatter to Q/K (b,h,n,32), Vt (b,h,64,n)
__global__ __launch_bounds__(256) void qkv_gemm(
    const short* __restrict__ Xt, const short* __restrict__ Wqkv, const float* __restrict__ Bqkv,
    short* __restrict__ Qo, short* __restrict__ Ko, short* __restrict__ Vto)
{
    __shared__ short At[128][40];  // +8 pad: 80B stride -> conflict-free b128
    __shared__ short Bt[128][40];
    int b = blockIdx.z, p0 = blockIdx.x * 128, o0 = blockIdx.y * 128;
    int t = threadIdx.x, wave = t >> 6, lane = t & 63;
    int wr = wave >> 1, wc = wave & 1, lr = lane & 15, lg = lane >> 4;

    const short* Abase = Xt + ((size_t)b * NSEQ + p0) * NCIN;
    const short* Bbase = Wqkv + (size_t)o0 * NCIN;

    f32x4 acc[4][4];
#pragma unroll
    for (int m = 0; m < 4; ++m)
#pragma unroll
        for (int n = 0; n < 4; ++n) acc[m][n] = (f32x4){0.f, 0.f, 0.f, 0.f};

    int srow = t >> 1, sch = (t & 1) * 16;
    for (int k0 = 0; k0 < NCIN; k0 += 32) {
        const int4* ga = (const int4*)(Abase + (size_t)srow * NCIN + k0 + sch);
        const int4* gb = (const int4*)(Bbase + (size_t)srow * NCIN + k0 + sch);
        int4 a0 = ga[0], a1 = ga[1];
        int4 b0 = gb[0], b1 = gb[1];
        *(int4*)&At[srow][sch]     = a0;
        *(int4*)&At[srow][sch + 8] = a1;
        *(int4*)&Bt[srow][sch]     = b0;
        *(int4*)&Bt[srow][sch + 8] = b1;
        __syncthreads();
        bf16x8 af[4], bfr[4];
#pragma unroll
        for (int m = 0; m < 4; ++m) af[m] = *(const bf16x8*)&At[wr * 64 + m * 16 + lr][lg * 8];
#pragma unroll
        for (int n = 0; n < 4; ++n) bfr[n] = *(const bf16x8*)&Bt[wc * 64 + n * 16 + lr][lg * 8];
#pragma unroll
        for (int m = 0; m < 4; ++m)
#pragma unroll
            for (int n = 0; n < 4; ++n)
                acc[m][n] = MFMA16(af[m], bfr[n], acc[m][n]);
        __syncthreads();
    }

#pragma unroll
    for (int n = 0; n < 4; ++n) {
        int o = o0 + wc * 64 + n * 16 + lr;
        float bias = Bqkv[o];
#pragma unroll
        for (int m = 0; m < 4; ++m) {
            int pr = p0 + wr * 64 + m * 16 + lg * 4;
#pragma unroll
            for (int r = 0; r < 4; ++r) {
                float y = acc[m][n][r] + bias;
                short vv = f2bf(y);
                int p = pr + r;
                if (o < 256) {
                    int hh = o >> 5, d = o & 31;
                    Qo[(((size_t)b * NHEADS + hh) * NSEQ + p) * NDK + d] = vv;
                } else if (o < 512) {
                    int oo = o - 256, hh = oo >> 5, d = oo & 31;
                    Ko[(((size_t)b * NHEADS + hh) * NSEQ + p) * NDK + d] = vv;
                } else {
                    int oo = o - 512, hh = oo >> 6, d = oo & 63;
                    Vto[(((size_t)b * NHEADS + hh) * NDV + d) * NSEQ + p] = vv;
                }
            }
        }
    }
}

// ---------------- K3: flash attention + GELU ----------------
__global__ __launch_bounds__(256) void attn_kernel(
    const short* __restrict__ Q, const short* __restrict__ K, const short* __restrict__ Vt,
    const float* __restrict__ pos_emb, short* __restrict__ Xg)
{
    __shared__ float pe[1024];
    __shared__ short P_lds[4][32][72];  // per-wave, 144B row stride (16B-aligned, banks spread)
    int b = blockIdx.z, h = blockIdx.y, qt = blockIdx.x;
    int t = threadIdx.x, wave = t >> 6, lane = t & 63;
    int lr = lane & 15, lg = lane >> 4;

    for (int i = t; i < 1024; i += 256)
        pe[i] = pos_emb[i * NHEADS + h] * 5.656854249492381f;  // bias/scale = pe*sqrt(32)
    __syncthreads();

    size_t bh = (size_t)b * NHEADS + h;
    const short* Qb = Q + bh * NSEQ * NDK;
    const short* Kb = K + bh * NSEQ * NDK;
    const short* Vb = Vt + bh * NDV * NSEQ;

    int q0 = qt * 128 + wave * 32;

    bf16x8 qf[2];
#pragma unroll
    for (int m = 0; m < 2; ++m)
        qf[m] = *(const bf16x8*)(Qb + (size_t)(q0 + m * 16 + lr) * NDK + lg * 8);

    int ir[2][4], ic[2][4];
#pragma unroll
    for (int m = 0; m < 2; ++m)
#pragma unroll
        for (int r = 0; r < 4; ++r) {
            int i = q0 + m * 16 + lg * 4 + r;
            ir[m][r] = i >> 5; ic[m][r] = i & 31;
        }

    float mrow[2][4], lsum[2][4];
#pragma unroll
    for (int m = 0; m < 2; ++m)
#pragma unroll
        for (int r = 0; r < 4; ++r) { mrow[m][r] = -1e30f; lsum[m][r] = 0.f; }

    f32x4 Oacc[2][4];
#pragma unroll
    for (int m = 0; m < 2; ++m)
#pragma unroll
        for (int d = 0; d < 4; ++d) Oacc[m][d] = (f32x4){0.f, 0.f, 0.f, 0.f};

    short (*pl)[72] = P_lds[wave];

    for (int j0 = 0; j0 < NSEQ; j0 += 64) {
        f32x4 s[2][4];
#pragma unroll
        for (int m = 0; m < 2; ++m)
#pragma unroll
            for (int n = 0; n < 4; ++n) s[m][n] = (f32x4){0.f, 0.f, 0.f, 0.f};

        bf16x8 kf[4];
#pragma unroll
        for (int n = 0; n < 4; ++n)
            kf[n] = *(const bf16x8*)(Kb + (size_t)(j0 + n * 16 + lr) * NDK + lg * 8);
#pragma unroll
        for (int m = 0; m < 2; ++m)
#pragma unroll
            for (int n = 0; n < 4; ++n)
                s[m][n] = MFMA16(qf[m], kf[n], s[m][n]);

#pragma unroll
        for (int n = 0; n < 4; ++n) {
            int j = j0 + n * 16 + lr;
            int jr = j >> 5, jc = j & 31;
#pragma unroll
            for (int m = 0; m < 2; ++m)
#pragma unroll
                for (int r = 0; r < 4; ++r) {
                    int dr = ir[m][r] - jr; dr = dr < 0 ? -dr : dr;
                    int dc = ic[m][r] - jc; dc = dc < 0 ? -dc : dc;
                    s[m][n][r] = s[m][n][r] * 0.17677669529663687f + pe[dr * 32 + dc];
                }
        }

#pragma unroll
        for (int m = 0; m < 2; ++m)
#pragma unroll
            for (int r = 0; r < 4; ++r) {
                float v = fmaxf(fmaxf(s[m][0][r], s[m][1][r]), fmaxf(s[m][2][r], s[m][3][r]));
                v = fmaxf(v, __shfl_xor(v, 1));
                v = fmaxf(v, __shfl_xor(v, 2));
                v = fmaxf(v, __shfl_xor(v, 4));
                v = fmaxf(v, __shfl_xor(v, 8));
                float mnew = fmaxf(mrow[m][r], v);
                float sf = __expf(mrow[m][r] - mnew);
                mrow[m][r] = mnew;
                float rs = 0.f;
#pragma unroll
                for (int n = 0; n < 4; ++n) {
                    float p = __expf(s[m][n][r] - mnew);
                    s[m][n][r] = p;
                    rs += p;
                }
                rs += __shfl_xor(rs, 1);
                rs += __shfl_xor(rs, 2);
                rs += __shfl_xor(rs, 4);
                rs += __shfl_xor(rs, 8);
                lsum[m][r] = lsum[m][r] * sf + rs;
#pragma unroll
                for (int d = 0; d < 4; ++d) Oacc[m][d][r] *= sf;
            }

        // P (C-layout) -> per-wave LDS -> A-fragments
#pragma unroll
        for (int m = 0; m < 2; ++m)
#pragma unroll
            for (int n = 0; n < 4; ++n)
#pragma unroll
                for (int r = 0; r < 4; ++r)
                    pl[m * 16 + lg * 4 + r][n * 16 + lr] = f2bf(s[m][n][r]);

#pragma unroll
        for (int ks = 0; ks < 2; ++ks) {
            bf16x8 vf[4];
#pragma unroll
            for (int d = 0; d < 4; ++d)
                vf[d] = *(const bf16x8*)(Vb + (size_t)(d * 16 + lr) * NSEQ + j0 + ks * 32 + lg * 8);
#pragma unroll
            for (int m = 0; m < 2; ++m) {
                bf16x8 pf = *(const bf16x8*)&pl[m * 16 + lr][ks * 32 + lg * 8];
#pragma unroll
                for (int d = 0; d < 4; ++d)
                    Oacc[m][d] = MFMA16(pf, vf[d], Oacc[m][d]);
            }
        }
    }

#pragma unroll
    for (int m = 0; m < 2; ++m)
#pragma unroll
        for (int d = 0; d < 4; ++d)
#pragma unroll
            for (int r = 0; r < 4; ++r) {
                float v = Oacc[m][d][r] / lsum[m][r];
                v = 0.5f * v * (1.f + erff(v * 0.70710678118654752f));  // exact GELU
                int p = q0 + m * 16 + lg * 4 + r;
                int ch = h * 64 + d * 16 + lr;
                Xg[((size_t)b * NSEQ + p) * 512 + ch] = f2bf(v);
            }
}

// ---------------- K4: output projection + bias + BN ----------------
__global__ __launch_bounds__(256) void out_gemm(
    const short* __restrict__ Xg, const short* __restrict__ Wo,
    const float* __restrict__ bo, const float* __restrict__ og, const float* __restrict__ ob,
    const float* __restrict__ om, const float* __restrict__ ov,
    float* __restrict__ out)
{
    __shared__ short At[128][40];
    __shared__ short Bt[64][40];
    int mt = blockIdx.x, nt = blockIdx.y;
    int t = threadIdx.x, wave = t >> 6, lane = t & 63;
    int wr = wave >> 1, wc = wave & 1, lr = lane & 15, lg = lane >> 4;
    int row0 = mt * 128, o0 = nt * 64;

    f32x4 acc[4][2];
#pragma unroll
    for (int m = 0; m < 4; ++m)
#pragma unroll
        for (int n = 0; n < 2; ++n) acc[m][n] = (f32x4){0.f, 0.f, 0.f, 0.f};

    int rowA = t >> 1, chA = (t & 1) * 16;
    int rowB = t >> 2, chB = (t & 3) * 8;
    for (int k0 = 0; k0 < 512; k0 += 32) {
        const int4* ga = (const int4*)(Xg + ((size_t)(row0 + rowA)) * 512 + k0 + chA);
        int4 a0 = ga[0], a1 = ga[1];
        int4 b0 = *(const int4*)(Wo + ((size_t)(o0 + rowB)) * 512 + k0 + chB);
        *(int4*)&At[rowA][chA]     = a0;
        *(int4*)&At[rowA][chA + 8] = a1;
        *(int4*)&Bt[rowB][chB]     = b0;
        __syncthreads();
        bf16x8 af[4], bfr[2];
#pragma unroll
        for (int m = 0; m < 4; ++m) af[m] = *(const bf16x8*)&At[wr * 64 + m * 16 + lr][lg * 8];
#pragma unroll
        for (int n = 0; n < 2; ++n) bfr[n] = *(const bf16x8*)&Bt[wc * 32 + n * 16 + lr][lg * 8];
#pragma unroll
        for (int m = 0; m < 4; ++m)
#pragma unroll
            for (int n = 0; n < 2; ++n)
                acc[m][n] = MFMA16(af[m], bfr[n], acc[m][n]);
        __syncthreads();
    }

    int b = row0 >> 10;
    int pbase = row0 & 1023;
#pragma unroll
    for (int n = 0; n < 2; ++n) {
        int o = o0 + wc * 32 + n * 16 + lr;
        float inv = og[o] * rsqrtf(ov[o] + 1e-5f);
        float off = bo[o] * inv + ob[o] - om[o] * inv;
        float* dst = out + ((size_t)b * 256 + o) * 1024 + pbase;
#pragma unroll
        for (int m = 0; m < 4; ++m)
#pragma unroll
            for (int r = 0; r < 4; ++r) {
                int p = wr * 64 + m * 16 + lg * 4 + r;
                dst[p] = acc[m][n][r] * inv + off;
            }
    }
}

// ---------------- launch ----------------
extern "C" void kernel_launch(void* const* d_in, const int* in_sizes, int n_in,
                              void* d_out, int out_size, void* d_ws, size_t ws_size,
                              hipStream_t stream) {
    const float* x     = (const float*)d_in[0];
    const float* wq    = (const float*)d_in[1];
    const float* qgam  = (const float*)d_in[2];
    const float* qbet  = (const float*)d_in[3];
    const float* qmu   = (const float*)d_in[4];
    const float* qvar  = (const float*)d_in[5];
    const float* wk    = (const float*)d_in[6];
    const float* kgam  = (const float*)d_in[7];
    const float* kbet  = (const float*)d_in[8];
    const float* kmu   = (const float*)d_in[9];
    const float* kvar  = (const float*)d_in[10];
    const float* wv    = (const float*)d_in[11];
    const float* vgam  = (const float*)d_in[12];
    const float* vbet  = (const float*)d_in[13];
    const float* vmu   = (const float*)d_in[14];
    const float* vvar  = (const float*)d_in[15];
    const float* wo    = (const float*)d_in[16];
    const float* bo    = (const float*)d_in[17];
    const float* ogam  = (const float*)d_in[18];
    const float* obet  = (const float*)d_in[19];
    const float* omu   = (const float*)d_in[20];
    const float* ovar  = (const float*)d_in[21];
    const float* pos_emb = (const float*)d_in[22];
    // d_in[23] pos_indices: recomputed analytically in-kernel

    char* ws = (char*)d_ws;
    short* Wqkv = (short*)(ws + 0);          // 1024*256*2 = 524288
    float* Bqkv = (float*)(ws + 524288);     // 4096
    short* Wo   = (short*)(ws + 528384);     // 262144
    short* Xt   = (short*)(ws + 790528);     // 4 MB
    short* Qd   = (short*)(ws + 4984832);    // 4 MB
    short* Kd   = (short*)(ws + 9179136);    // 4 MB
    short* Vtd  = (short*)(ws + 13373440);   // 8 MB
    short* Xg   = (short*)(ws + 21762048);   // 8 MB  (end 30150656)

    prep_kernel<<<1280, 256, 0, stream>>>(wq, qgam, qbet, qmu, qvar,
                                          wk, kgam, kbet, kmu, kvar,
                                          wv, vgam, vbet, vmu, vvar,
                                          wo, Wqkv, Bqkv, Wo);
    transpose_kernel<<<dim3(16, 4, NB), 256, 0, stream>>>(x, Xt);
    qkv_gemm<<<dim3(8, 8, NB), 256, 0, stream>>>(Xt, Wqkv, Bqkv, Qd, Kd, Vtd);
    attn_kernel<<<dim3(8, NHEADS, NB), 256, 0, stream>>>(Qd, Kd, Vtd, pos_emb, Xg);
    out_gemm<<<dim3(64, 4), 256, 0, stream>>>(Xg, Wo, bo, ogam, obet, omu, ovar, (float*)d_out);
}

// Round 2
// 98.425 us; speedup vs baseline: 1.2913x; 1.2913x over previous
//
#include <hip/hip_runtime.h>
#include <math.h>

#define NB 8
#define NHEADS 8
#define NDK 32
#define NDV 64
#define NSEQ 1024
#define NCIN 256

typedef __attribute__((ext_vector_type(8))) short bf16x8;
typedef __attribute__((ext_vector_type(4))) float f32x4;
typedef __attribute__((ext_vector_type(16))) float f32x16;

#define MFMA16(A, B, C) __builtin_amdgcn_mfma_f32_16x16x32_bf16(A, B, C, 0, 0, 0)
#define MFMA32(A, B, C) __builtin_amdgcn_mfma_f32_32x32x16_bf16(A, B, C, 0, 0, 0)

__device__ __forceinline__ short f2bf(float f) {
    union { float f; unsigned u; } v; v.f = f;
    unsigned r = v.u + 0x7FFFu + ((v.u >> 16) & 1u);
    return (short)(r >> 16);
}

// ---------------- K0: fold BN into weights, convert to bf16 ----------------
__global__ __launch_bounds__(256) void prep_kernel(
    const float* __restrict__ wq, const float* __restrict__ qg, const float* __restrict__ qb,
    const float* __restrict__ qm, const float* __restrict__ qv,
    const float* __restrict__ wk, const float* __restrict__ kg, const float* __restrict__ kb,
    const float* __restrict__ km, const float* __restrict__ kv,
    const float* __restrict__ wv, const float* __restrict__ vg, const float* __restrict__ vb,
    const float* __restrict__ vm, const float* __restrict__ vv,
    const float* __restrict__ wo,
    short* __restrict__ Wqkv, float* __restrict__ Bqkv, short* __restrict__ Wo)
{
    int row = blockIdx.x, t = threadIdx.x;
    if (row < 1024) {
        const float *w, *g, *be, *mu, *va; int o;
        if (row < 256)      { w = wq; o = row;       g = qg; be = qb; mu = qm; va = qv; }
        else if (row < 512) { w = wk; o = row - 256; g = kg; be = kb; mu = km; va = kv; }
        else                { w = wv; o = row - 512; g = vg; be = vb; mu = vm; va = vv; }
        float inv = g[o] * rsqrtf(va[o] + 1e-5f);
        Wqkv[row * NCIN + t] = f2bf(w[o * NCIN + t] * inv);
        if (t == 0) Bqkv[row] = be[o] - mu[o] * inv;
    } else {
        int o = row - 1024;
        Wo[o * 512 + t]       = f2bf(wo[o * 512 + t]);
        Wo[o * 512 + 256 + t] = f2bf(wo[o * 512 + 256 + t]);
    }
}

// ---------------- K1: x (b,c,p) f32 -> Xt (b,p,c) bf16 ----------------
__global__ __launch_bounds__(256) void transpose_kernel(const float* __restrict__ x, short* __restrict__ Xt)
{
    __shared__ float tile[64][65];
    int b = blockIdx.z, p0 = blockIdx.x * 64, c0 = blockIdx.y * 64;
    int t = threadIdx.x, tp = t & 63, tr = t >> 6;
    const float* xb = x + ((size_t)b * NCIN + c0) * NSEQ + p0;
#pragma unroll
    for (int i = 0; i < 16; ++i) {
        int cl = tr * 16 + i;
        tile[cl][tp] = xb[(size_t)cl * NSEQ + tp];
    }
    __syncthreads();
    short* xt = Xt + ((size_t)b * NSEQ + p0) * NCIN + c0;
#pragma unroll
    for (int i = 0; i < 16; ++i) {
        int pl = tr * 16 + i;
        xt[(size_t)pl * NCIN + tp] = f2bf(tile[tp][pl]);
    }
}

// ---------------- K2: QKV projection GEMM ----------------
__global__ __launch_bounds__(256) void qkv_gemm(
    const short* __restrict__ Xt, const short* __restrict__ Wqkv, const float* __restrict__ Bqkv,
    short* __restrict__ Qo, short* __restrict__ Ko, short* __restrict__ Vto)
{
    __shared__ short At[128][40];
    __shared__ short Bt[128][40];
    int b = blockIdx.z, p0 = blockIdx.x * 128, o0 = blockIdx.y * 128;
    int t = threadIdx.x, wave = t >> 6, lane = t & 63;
    int wr = wave >> 1, wc = wave & 1, lr = lane & 15, lg = lane >> 4;

    const short* Abase = Xt + ((size_t)b * NSEQ + p0) * NCIN;
    const short* Bbase = Wqkv + (size_t)o0 * NCIN;

    f32x4 acc[4][4];
#pragma unroll
    for (int m = 0; m < 4; ++m)
#pragma unroll
        for (int n = 0; n < 4; ++n) acc[m][n] = (f32x4){0.f, 0.f, 0.f, 0.f};

    int srow = t >> 1, sch = (t & 1) * 16;
    for (int k0 = 0; k0 < NCIN; k0 += 32) {
        const int4* ga = (const int4*)(Abase + (size_t)srow * NCIN + k0 + sch);
        const int4* gb = (const int4*)(Bbase + (size_t)srow * NCIN + k0 + sch);
        int4 a0 = ga[0], a1 = ga[1];
        int4 b0 = gb[0], b1 = gb[1];
        *(int4*)&At[srow][sch]     = a0;
        *(int4*)&At[srow][sch + 8] = a1;
        *(int4*)&Bt[srow][sch]     = b0;
        *(int4*)&Bt[srow][sch + 8] = b1;
        __syncthreads();
        bf16x8 af[4], bfr[4];
#pragma unroll
        for (int m = 0; m < 4; ++m) af[m] = *(const bf16x8*)&At[wr * 64 + m * 16 + lr][lg * 8];
#pragma unroll
        for (int n = 0; n < 4; ++n) bfr[n] = *(const bf16x8*)&Bt[wc * 64 + n * 16 + lr][lg * 8];
#pragma unroll
        for (int m = 0; m < 4; ++m)
#pragma unroll
            for (int n = 0; n < 4; ++n)
                acc[m][n] = MFMA16(af[m], bfr[n], acc[m][n]);
        __syncthreads();
    }

#pragma unroll
    for (int n = 0; n < 4; ++n) {
        int o = o0 + wc * 64 + n * 16 + lr;
        float bias = Bqkv[o];
#pragma unroll
        for (int m = 0; m < 4; ++m) {
            int pr = p0 + wr * 64 + m * 16 + lg * 4;
#pragma unroll
            for (int r = 0; r < 4; ++r) {
                float y = acc[m][n][r] + bias;
                short vv = f2bf(y);
                int p = pr + r;
                if (o < 256) {
                    int hh = o >> 5, d = o & 31;
                    Qo[(((size_t)b * NHEADS + hh) * NSEQ + p) * NDK + d] = vv;
                } else if (o < 512) {
                    int oo = o - 256, hh = oo >> 5, d = oo & 31;
                    Ko[(((size_t)b * NHEADS + hh) * NSEQ + p) * NDK + d] = vv;
                } else {
                    int oo = o - 512, hh = oo >> 6, d = oo & 63;
                    Vto[(((size_t)b * NHEADS + hh) * NDV + d) * NSEQ + p] = vv;
                }
            }
        }
    }
}

// ---------------- K3: flash attention + GELU (swapped-operand 32x32) ----------------
// 1 wave per WG, 32 q-rows per wave. S^T = mfma(K,Q): lane owns q = lane&31,
// keys j = (r&3)+8*(r>>2)+4*hi per fragment. O^T = mfma(V^T, P): cols = q -> stats lane-local.
__global__ __launch_bounds__(64) void attn_kernel(
    const short* __restrict__ Q, const short* __restrict__ K, const short* __restrict__ Vt,
    const float* __restrict__ pos_emb, short* __restrict__ Xg)
{
    __shared__ float pe[1024];
    __shared__ short tb[32][72];

    int bid = blockIdx.x;
    int h = bid & 7;                 // bid%8 = head -> per-XCD K/V working set 8b*192KB = 1.5MB (L2-fit)
    int qt = (bid >> 3) & 31;
    int b = bid >> 8;
    int l = threadIdx.x, ql = l & 31, hi = l >> 5;

    for (int i = l; i < 1024; i += 64)
        pe[i] = pos_emb[i * NHEADS + h] * 5.656854249492381f;  // bias/scale = pe*sqrt(32)
    __syncthreads();

    size_t bh = (size_t)b * NHEADS + h;
    const short* Qb = Q + bh * NSEQ * NDK;
    const short* Kb = K + bh * NSEQ * NDK;
    const short* Vb = Vt + bh * NDV * NSEQ;

    int q0 = qt * 32;
    int iq = q0 + ql;
    int ir = iq >> 5, ic = iq & 31;

    bf16x8 qf0 = *(const bf16x8*)(Qb + (size_t)iq * NDK + hi * 8);
    bf16x8 qf1 = *(const bf16x8*)(Qb + (size_t)iq * NDK + 16 + hi * 8);

    float mrow = -1e30f, lsum = 0.f;
    f32x16 O0, O1;
#pragma unroll
    for (int r = 0; r < 16; ++r) { O0[r] = 0.f; O1[r] = 0.f; }

    for (int j0 = 0; j0 < NSEQ; j0 += 32) {
        // K A-fragments: A[row=j=ql][k=d]
        bf16x8 kf0 = *(const bf16x8*)(Kb + (size_t)(j0 + ql) * NDK + hi * 8);
        bf16x8 kf1 = *(const bf16x8*)(Kb + (size_t)(j0 + ql) * NDK + 16 + hi * 8);
        f32x16 S;
#pragma unroll
        for (int r = 0; r < 16; ++r) S[r] = 0.f;
        S = MFMA32(kf0, qf0, S);
        S = MFMA32(kf1, qf1, S);

        // V^T A-fragments for PV (issued early: L2 latency hides under softmax)
        bf16x8 vf[4];
#pragma unroll
        for (int dn = 0; dn < 2; ++dn)
#pragma unroll
            for (int ks = 0; ks < 2; ++ks)
                vf[dn * 2 + ks] = *(const bf16x8*)(Vb + (size_t)(dn * 32 + ql) * NSEQ + j0 + ks * 16 + hi * 8);

        // bias: dr constant per tile (j0 32-aligned), dc per reg
        int drb = ir - (j0 >> 5); drb = drb < 0 ? -drb : drb;
        const float* per = pe + drb * 32;
#pragma unroll
        for (int r = 0; r < 16; ++r) {
            int jc = (r & 3) + 8 * (r >> 2) + 4 * hi;
            int dc = ic - jc; dc = dc < 0 ? -dc : dc;
            S[r] = S[r] * 0.17677669529663687f + per[dc];
        }

        // online softmax: 16 in-lane + partner(lane^32)
        float pmax = S[0];
#pragma unroll
        for (int r = 1; r < 16; ++r) pmax = fmaxf(pmax, S[r]);
        pmax = fmaxf(pmax, __shfl_xor(pmax, 32));
        float mnew = fmaxf(mrow, pmax);
        float sf = __expf(mrow - mnew);
        mrow = mnew;
        float rs = 0.f;
#pragma unroll
        for (int r = 0; r < 16; ++r) { float p = __expf(S[r] - mnew); S[r] = p; rs += p; }
        rs += __shfl_xor(rs, 32);
        lsum = lsum * sf + rs;
#pragma unroll
        for (int r = 0; r < 16; ++r) { O0[r] *= sf; O1[r] *= sf; }

        // pack P to bf16 pairs: pk[a][u] = (S[4a+2u], S[4a+2u+1])
        int pk[4][2];
#pragma unroll
        for (int a = 0; a < 4; ++a)
#pragma unroll
            for (int u = 0; u < 2; ++u) {
                unsigned lo = (unsigned short)f2bf(S[4 * a + 2 * u]);
                unsigned hi16 = (unsigned short)f2bf(S[4 * a + 2 * u + 1]);
                pk[a][u] = (int)(lo | (hi16 << 16));
            }

        // rebuild P fragment in-register: j = 16ks + 8hi + e needs own pk[2ks+hi] + partner pk[2ks+hi]
#pragma unroll
        for (int ks = 0; ks < 2; ++ks) {
            int s0 = hi ? pk[2 * ks][0] : pk[2 * ks + 1][0];
            int s1 = hi ? pk[2 * ks][1] : pk[2 * ks + 1][1];
            int w0 = __shfl_xor(s0, 32);
            int w1 = __shfl_xor(s1, 32);
            union { bf16x8 v; unsigned u[4]; } pf;
            pf.u[0] = hi ? (unsigned)w0 : (unsigned)pk[2 * ks][0];
            pf.u[1] = hi ? (unsigned)w1 : (unsigned)pk[2 * ks][1];
            pf.u[2] = hi ? (unsigned)pk[2 * ks + 1][0] : (unsigned)w0;
            pf.u[3] = hi ? (unsigned)pk[2 * ks + 1][1] : (unsigned)w1;
            // O^T[d][q] += V^T[d][j] * P^T[j][q]  (same regs serve as B-operand)
            O0 = MFMA32(vf[ks], pf.v, O0);
            O1 = MFMA32(vf[2 + ks], pf.v, O1);
        }
    }

    float invl = 1.0f / lsum;
    // epilogue: O^T (cols=q) -> LDS transpose -> Xg[p][512] rows (out_gemm layout unchanged)
#pragma unroll
    for (int dn = 0; dn < 2; ++dn)
#pragma unroll
        for (int a = 0; a < 4; ++a) {
            short4 w;
#pragma unroll
            for (int bb = 0; bb < 4; ++bb) {
                float v = (dn ? O1[4 * a + bb] : O0[4 * a + bb]) * invl;
                v = 0.5f * v * (1.f + erff(v * 0.70710678118654752f));  // exact GELU
                ((short*)&w)[bb] = f2bf(v);
            }
            *(short4*)&tb[ql][dn * 32 + 8 * a + 4 * hi] = w;
        }
    __syncthreads();
#pragma unroll
    for (int c = 0; c < 4; ++c) {
        int4 val = *(const int4*)&tb[ql][(hi * 4 + c) * 8];
        *(int4*)(Xg + ((size_t)b * NSEQ + q0 + ql) * 512 + h * 64 + (hi * 4 + c) * 8) = val;
    }
}

// ---------------- K4: output projection + bias + BN ----------------
__global__ __launch_bounds__(256) void out_gemm(
    const short* __restrict__ Xg, const short* __restrict__ Wo,
    const float* __restrict__ bo, const float* __restrict__ og, const float* __restrict__ ob,
    const float* __restrict__ om, const float* __restrict__ ov,
    float* __restrict__ out)
{
    __shared__ short At[128][40];
    __shared__ short Bt[64][40];
    int mt = blockIdx.x, nt = blockIdx.y;
    int t = threadIdx.x, wave = t >> 6, lane = t & 63;
    int wr = wave >> 1, wc = wave & 1, lr = lane & 15, lg = lane >> 4;
    int row0 = mt * 128, o0 = nt * 64;

    f32x4 acc[4][2];
#pragma unroll
    for (int m = 0; m < 4; ++m)
#pragma unroll
        for (int n = 0; n < 2; ++n) acc[m][n] = (f32x4){0.f, 0.f, 0.f, 0.f};

    int rowA = t >> 1, chA = (t & 1) * 16;
    int rowB = t >> 2, chB = (t & 3) * 8;
    for (int k0 = 0; k0 < 512; k0 += 32) {
        const int4* ga = (const int4*)(Xg + ((size_t)(row0 + rowA)) * 512 + k0 + chA);
        int4 a0 = ga[0], a1 = ga[1];
        int4 b0 = *(const int4*)(Wo + ((size_t)(o0 + rowB)) * 512 + k0 + chB);
        *(int4*)&At[rowA][chA]     = a0;
        *(int4*)&At[rowA][chA + 8] = a1;
        *(int4*)&Bt[rowB][chB]     = b0;
        __syncthreads();
        bf16x8 af[4], bfr[2];
#pragma unroll
        for (int m = 0; m < 4; ++m) af[m] = *(const bf16x8*)&At[wr * 64 + m * 16 + lr][lg * 8];
#pragma unroll
        for (int n = 0; n < 2; ++n) bfr[n] = *(const bf16x8*)&Bt[wc * 32 + n * 16 + lr][lg * 8];
#pragma unroll
        for (int m = 0; m < 4; ++m)
#pragma unroll
            for (int n = 0; n < 2; ++n)
                acc[m][n] = MFMA16(af[m], bfr[n], acc[m][n]);
        __syncthreads();
    }

    int b = row0 >> 10;
    int pbase = row0 & 1023;
#pragma unroll
    for (int n = 0; n < 2; ++n) {
        int o = o0 + wc * 32 + n * 16 + lr;
        float inv = og[o] * rsqrtf(ov[o] + 1e-5f);
        float off = bo[o] * inv + ob[o] - om[o] * inv;
        float* dst = out + ((size_t)b * 256 + o) * 1024 + pbase;
#pragma unroll
        for (int m = 0; m < 4; ++m)
#pragma unroll
            for (int r = 0; r < 4; ++r) {
                int p = wr * 64 + m * 16 + lg * 4 + r;
                dst[p] = acc[m][n][r] * inv + off;
            }
    }
}

// ---------------- launch ----------------
extern "C" void kernel_launch(void* const* d_in, const int* in_sizes, int n_in,
                              void* d_out, int out_size, void* d_ws, size_t ws_size,
                              hipStream_t stream) {
    const float* x     = (const float*)d_in[0];
    const float* wq    = (const float*)d_in[1];
    const float* qgam  = (const float*)d_in[2];
    const float* qbet  = (const float*)d_in[3];
    const float* qmu   = (const float*)d_in[4];
    const float* qvar  = (const float*)d_in[5];
    const float* wk    = (const float*)d_in[6];
    const float* kgam  = (const float*)d_in[7];
    const float* kbet  = (const float*)d_in[8];
    const float* kmu   = (const float*)d_in[9];
    const float* kvar  = (const float*)d_in[10];
    const float* wv    = (const float*)d_in[11];
    const float* vgam  = (const float*)d_in[12];
    const float* vbet  = (const float*)d_in[13];
    const float* vmu   = (const float*)d_in[14];
    const float* vvar  = (const float*)d_in[15];
    const float* wo    = (const float*)d_in[16];
    const float* bo    = (const float*)d_in[17];
    const float* ogam  = (const float*)d_in[18];
    const float* obet  = (const float*)d_in[19];
    const float* omu   = (const float*)d_in[20];
    const float* ovar  = (const float*)d_in[21];
    const float* pos_emb = (const float*)d_in[22];
    // d_in[23] pos_indices: recomputed analytically in-kernel

    char* ws = (char*)d_ws;
    short* Wqkv = (short*)(ws + 0);          // 1024*256*2 = 524288
    float* Bqkv = (float*)(ws + 524288);     // 4096
    short* Wo   = (short*)(ws + 528384);     // 262144
    short* Xt   = (short*)(ws + 790528);     // 4 MB
    short* Qd   = (short*)(ws + 4984832);    // 4 MB
    short* Kd   = (short*)(ws + 9179136);    // 4 MB
    short* Vtd  = (short*)(ws + 13373440);   // 8 MB
    short* Xg   = (short*)(ws + 21762048);   // 8 MB  (end 30150656)

    prep_kernel<<<1280, 256, 0, stream>>>(wq, qgam, qbet, qmu, qvar,
                                          wk, kgam, kbet, kmu, kvar,
                                          wv, vgam, vbet, vmu, vvar,
                                          wo, Wqkv, Bqkv, Wo);
    transpose_kernel<<<dim3(16, 4, NB), 256, 0, stream>>>(x, Xt);
    qkv_gemm<<<dim3(8, 8, NB), 256, 0, stream>>>(Xt, Wqkv, Bqkv, Qd, Kd, Vtd);
    attn_kernel<<<2048, 64, 0, stream>>>(Qd, Kd, Vtd, pos_emb, Xg);
    out_gemm<<<dim3(64, 4), 256, 0, stream>>>(Xg, Wo, bo, ogam, obet, omu, ovar, (float*)d_out);
}